// Round 13
// baseline (138.705 us; speedup 1.0000x reference)
//
#include <hip/hip_runtime.h>
#include <hip/hip_bf16.h>
#include <cstdint>
#include <cstddef>

// Problem dims (fixed by the reference)
#define NEXP   8
#define BATCH  8
#define NTOK   2048
#define DDIM   512
#define DFFDIM 2048
#define DCOND  512

typedef float  f32x4  __attribute__((ext_vector_type(4)));
typedef __bf16 bf16x8 __attribute__((ext_vector_type(8)));

using as1_cvoid = __attribute__((address_space(1))) const void;
using as3_void  = __attribute__((address_space(3))) void;

__device__ __forceinline__ void async_copy16(const void* g, void* l) {
  __builtin_amdgcn_global_load_lds((as1_cvoid*)g, (as3_void*)l, 16, 0, 0);
}

__device__ __forceinline__ unsigned short f2bf_bits(float f) {
  __hip_bfloat16 h = __float2bfloat16(f);
  return *reinterpret_cast<unsigned short*>(&h);
}

// fast tanh-approx gelu: 0.5v(1+tanh(z)) == v * sigmoid(2z)
__device__ __forceinline__ float gelu_fast(float v) {
  float y = v * fmaf(0.0713548162726f, v * v, 1.5957691216057f);
  float e = exp2f(-1.44269504089f * y);
  return v * __builtin_amdgcn_rcpf(1.0f + e);
}

// ---------------------------------------------------------------------------
// 1) scale/shift = cond[b] @ W_cond[route[b]] + b_cond[route[b]] -> ss[B][1024]
// ---------------------------------------------------------------------------
__global__ void mod_kernel(const float* __restrict__ cond,
                           const int* __restrict__ route,
                           const float* __restrict__ W_cond,
                           const float* __restrict__ b_cond,
                           float* __restrict__ ss) {
  const int b = blockIdx.y;
  const int m = route[b];
  const int tj = threadIdx.x & 63;
  const int cq = threadIdx.x >> 6;            // 0..3
  const int j = blockIdx.x * 64 + tj;
  const float* wc = W_cond + (size_t)m * DCOND * (2 * DDIM);
  const float* cb = cond + (size_t)b * DCOND;
  float acc = 0.f;
#pragma unroll 4
  for (int c = cq * 128; c < cq * 128 + 128; ++c)
    acc += cb[c] * wc[(size_t)c * (2 * DDIM) + j];
  __shared__ float red[4][64];
  red[cq][tj] = acc;
  __syncthreads();
  if (cq == 0) {
    float v = red[0][tj] + red[1][tj] + red[2][tj] + red[3][tj];
    ss[(size_t)b * (2 * DDIM) + j] = v + b_cond[(size_t)m * (2 * DDIM) + j];
  }
}

// ---------------------------------------------------------------------------
// 2) x_mod = bf16( x * (1+scale) + shift )   [B][N][D] bf16
// ---------------------------------------------------------------------------
__global__ void film_kernel(const float* __restrict__ x,
                            const float* __restrict__ ss,
                            __hip_bfloat16* __restrict__ xmod) {
  const size_t idx = (size_t)blockIdx.x * blockDim.x + threadIdx.x;
  const int d4 = (int)(idx & (DDIM / 4 - 1));
  const int b  = (int)(idx >> 18);
  const float4 xv = reinterpret_cast<const float4*>(x)[idx];
  const float4 sc = reinterpret_cast<const float4*>(ss + (size_t)b * 1024)[d4];
  const float4 sh = reinterpret_cast<const float4*>(ss + (size_t)b * 1024 + DDIM)[d4];
  float r0 = xv.x * (1.f + sc.x) + sh.x;
  float r1 = xv.y * (1.f + sc.y) + sh.y;
  float r2 = xv.z * (1.f + sc.z) + sh.z;
  float r3 = xv.w * (1.f + sc.w) + sh.w;
  ushort4 ov;
  ov.x = f2bf_bits(r0); ov.y = f2bf_bits(r1);
  ov.z = f2bf_bits(r2); ov.w = f2bf_bits(r3);
  reinterpret_cast<ushort4*>(xmod)[idx] = ov;
}

// ---------------------------------------------------------------------------
// 3) transpose + f32->bf16:  in [M][L][R] f32  ->  out [M][R][L] bf16
// ---------------------------------------------------------------------------
__global__ void transpose_cvt(const float* __restrict__ in,
                              __hip_bfloat16* __restrict__ outp,
                              int L, int R,
                              const int* __restrict__ route) {
  const int mi = blockIdx.z;
  bool used = false;
#pragma unroll
  for (int b = 0; b < BATCH; ++b) used |= (route[b] == mi);
  if (!used) return;

  __shared__ float tile[32][33];
  const float* inm = in + (size_t)mi * L * R;
  __hip_bfloat16* outm = outp + (size_t)mi * L * R;
  const int r0 = blockIdx.x * 32, l0 = blockIdx.y * 32;
  const int tx = threadIdx.x, ty = threadIdx.y;
#pragma unroll
  for (int i = 0; i < 32; i += 8)
    tile[ty + i][tx] = inm[(size_t)(l0 + ty + i) * R + r0 + tx];
  __syncthreads();
#pragma unroll
  for (int i = 0; i < 32; i += 8)
    outm[(size_t)(r0 + ty + i) * L + l0 + tx] = __float2bfloat16(tile[tx][ty + i]);
}

// ---------------------------------------------------------------------------
// 4a) 4-BARRIER 8-PHASE GEMM1 (R12-proven, unchanged): BM=BN=256, BK=64,
//     512 threads = 8 waves (2M x 4N), wave-tile 128x64.
// ---------------------------------------------------------------------------
template <int EPI>
__global__ __launch_bounds__(512, 1) void gemm_8ph(
    const __hip_bfloat16* __restrict__ A,
    const __hip_bfloat16* __restrict__ Btb,
    const float* __restrict__ biasbase,
    void* __restrict__ outbase,
    const int* __restrict__ route,
    int Mdim, int Ndim, int Kdim, int tilesX) {
  const int bid  = blockIdx.x;
  const int b    = bid & 7;            // batch -> XCD
  const int tile = bid >> 3;
  const int bx   = tile % tilesX;
  const int by   = tile / tilesX;
  const int m = route[b];
  const __hip_bfloat16* Ab = A   + (size_t)b * Mdim * Kdim;
  const __hip_bfloat16* Bt = Btb + (size_t)m * Ndim * Kdim;
  const float* bias = biasbase + (size_t)m * Ndim;
  const int r0 = bx * 256;
  const int n0 = by * 256;

  __shared__ alignas(16) __hip_bfloat16 As[2][2][128 * 64];  // 64 KB
  __shared__ alignas(16) __hip_bfloat16 Bs[2][2][128 * 64];  // 64 KB

  const int t = threadIdx.x;
  const int w = t >> 6, l = t & 63;
  const int wm = w >> 2;               // 0..1  (M half, 128 rows)
  const int wn = w & 3;                // 0..3  (N quarter, 64 cols)

  const int srow = t >> 3;                     // 0..63
  const int scol = (t & 7) ^ ((t >> 3) & 7);   // inverse-swizzled 16B chunk

#define STAGE_AH(sb, ha, k0)                                                  \
  { async_copy16(Ab + (size_t)(r0 + (ha) * 128 + srow) * Kdim + (k0) + scol * 8, \
                 &As[sb][ha][(size_t)t * 8]);                                 \
    async_copy16(Ab + (size_t)(r0 + (ha) * 128 + 64 + srow) * Kdim + (k0) + scol * 8, \
                 &As[sb][ha][(size_t)(512 + t) * 8]); }
#define STAGE_BH(sb, hb, k0)                                                  \
  { async_copy16(Bt + (size_t)(n0 + (hb) * 128 + srow) * Kdim + (k0) + scol * 8, \
                 &Bs[sb][hb][(size_t)t * 8]);                                 \
    async_copy16(Bt + (size_t)(n0 + (hb) * 128 + 64 + srow) * Kdim + (k0) + scol * 8, \
                 &Bs[sb][hb][(size_t)(512 + t) * 8]); }

  const int lrow = l & 15, lq = l >> 4, lx = l & 7;

#define LOAD_A(mh)                                                            \
  { _Pragma("unroll")                                                         \
    for (int i = 0; i < 4; ++i) {                                             \
      const int row = ((mh) * 4 + i) * 16 + lrow;                             \
      aF[i][0] = *reinterpret_cast<const bf16x8*>(&aH[(row * 8 + ((0 + lq) ^ lx)) * 8]); \
      aF[i][1] = *reinterpret_cast<const bf16x8*>(&aH[(row * 8 + ((4 + lq) ^ lx)) * 8]); \
    } }
#define LOAD_B(nh)                                                            \
  { _Pragma("unroll")                                                         \
    for (int j = 0; j < 2; ++j) {                                             \
      const int row = (wn & 1) * 64 + ((nh) * 2 + j) * 16 + lrow;             \
      bF[nh][j][0] = *reinterpret_cast<const bf16x8*>(&bH[(row * 8 + ((0 + lq) ^ lx)) * 8]); \
      bF[nh][j][1] = *reinterpret_cast<const bf16x8*>(&bH[(row * 8 + ((4 + lq) ^ lx)) * 8]); \
    } }
#define MFMA_Q(mh, nh)                                                        \
  { __builtin_amdgcn_s_setprio(1);                                            \
    _Pragma("unroll")                                                         \
    for (int i = 0; i < 4; ++i)                                               \
      _Pragma("unroll")                                                       \
      for (int j = 0; j < 2; ++j) {                                           \
        acc[(mh) * 4 + i][(nh) * 2 + j] = __builtin_amdgcn_mfma_f32_16x16x32_bf16( \
            aF[i][0], bF[nh][j][0], acc[(mh) * 4 + i][(nh) * 2 + j], 0, 0, 0);\
        acc[(mh) * 4 + i][(nh) * 2 + j] = __builtin_amdgcn_mfma_f32_16x16x32_bf16( \
            aF[i][1], bF[nh][j][1], acc[(mh) * 4 + i][(nh) * 2 + j], 0, 0, 0);\
      }                                                                       \
    __builtin_amdgcn_s_setprio(0); }
#define BARSCHED  { __builtin_amdgcn_s_barrier(); __builtin_amdgcn_sched_barrier(0); }

  f32x4 acc[8][4] = {};
  const int nt = Kdim >> 6;

  STAGE_BH(0, 0, 0)
  STAGE_AH(0, 0, 0)
  STAGE_AH(0, 1, 0)
  STAGE_BH(0, 1, 0)
  if (nt > 1) { STAGE_BH(1, 0, 64) STAGE_AH(1, 0, 64) }

  for (int kt = 0; kt < nt; ++kt) {
    const int s = kt & 1;
    if (kt == nt - 1) { asm volatile("s_waitcnt vmcnt(0)" ::: "memory"); }
    else              { asm volatile("s_waitcnt vmcnt(4)" ::: "memory"); }
    BARSCHED

    const __hip_bfloat16* aH = As[s][wm];
    const __hip_bfloat16* bH = Bs[s][wn >> 1];
    bf16x8 aF[4][2], bF[2][2][2];

    LOAD_A(0)
    LOAD_B(0)
    if (kt + 1 < nt) STAGE_AH(s ^ 1, 1, (kt + 1) * 64)
    MFMA_Q(0, 0)
    BARSCHED

    LOAD_B(1)
    if (kt + 1 < nt) STAGE_BH(s ^ 1, 1, (kt + 1) * 64)
    MFMA_Q(0, 1)
    BARSCHED

    LOAD_A(1)
    if (kt + 2 < nt) STAGE_BH(s, 0, (kt + 2) * 64)
    MFMA_Q(1, 0)
    BARSCHED

    if (kt + 2 < nt) STAGE_AH(s, 0, (kt + 2) * 64)
    MFMA_Q(1, 1)
  }
#undef STAGE_AH
#undef STAGE_BH
#undef LOAD_A
#undef LOAD_B
#undef MFMA_Q
#undef BARSCHED

  if (EPI == 0) {
    __hip_bfloat16* out = (__hip_bfloat16*)outbase + (size_t)b * Mdim * Ndim;
#pragma unroll
    for (int mb = 0; mb < 8; ++mb) {
      const int row = r0 + wm * 128 + mb * 16 + lq * 4;
#pragma unroll
      for (int nb = 0; nb < 4; ++nb) {
        const int col = n0 + wn * 64 + nb * 16 + lrow;
        const float bv = bias[col];
#pragma unroll
        for (int j = 0; j < 4; ++j) {
          float g = gelu_fast(acc[mb][nb][j] + bv);
          out[(size_t)(row + j) * Ndim + col] = __float2bfloat16(g);
        }
      }
    }
  } else {
    float* out = (float*)outbase + (size_t)b * Mdim * Ndim;
#pragma unroll
    for (int mb = 0; mb < 8; ++mb) {
      const int row = r0 + wm * 128 + mb * 16 + lq * 4;
#pragma unroll
      for (int nb = 0; nb < 4; ++nb) {
        const int col = n0 + wn * 64 + nb * 16 + lrow;
        const float bv = bias[col];
#pragma unroll
        for (int j = 0; j < 4; ++j)
          out[(size_t)(row + j) * Ndim + col] = acc[mb][nb][j] + bv;
      }
    }
  }
}

// ---------------------------------------------------------------------------
// 4b) 4-BARRIER 8-PHASE GEMM2: BM=256, BN=128, BK=64, 256 threads = 4 waves
//     (2M x 2N), wave-tile 128x64 (best LDS/MFMA ratio, 375B/MFMA).
//     Grid 8*4*8 = 256 blocks = exactly 1/CU, single round; nt=32 amortizes
//     fill (m248 regime: grouped-GEMM K>=1024 + 8ph = +10% over 2ph).
//     LDS 96 KB: As[2][2][128x64] (A-half 128 rows, 4 loads/thread),
//     Bs[2][2][64x64] (B-half 64 rows, 2 loads/thread).
//     Schedule per K-tile (R12 structure): ph0 {read A0+B0; stage A1(k+1)[4]
//     ->opp; Q00} bar; ph1 {read B1; stage B1(k+1)[2]->opp; Q01} bar;
//     ph2 {read A1; stage B0(k+2)[2]->cur; Q10} bar; ph3 {stage A0(k+2)[4]
//     ->cur; Q11}; loop-top wait+bar.  Entry vmcnt(6): newest 6 ops =
//     B0(kt+1)[2]+A0(kt+1)[4] staged last tile's ph2/ph3; retires all of
//     tile kt.  Safety: all B reads done by ph1-end barrier -> B0(kt+2)
//     stage at ph2 OK; all A reads by ph2-end -> A0(kt+2) at ph3 OK.
//     Swizzle: R6-proven 8-chunk pattern verbatim.
// ---------------------------------------------------------------------------
__global__ __launch_bounds__(256, 1) void gemm2_8ph4w(
    const __hip_bfloat16* __restrict__ A,
    const __hip_bfloat16* __restrict__ Btb,
    const float* __restrict__ biasbase,
    float* __restrict__ outb,
    const int* __restrict__ route,
    int Mdim, int Ndim, int Kdim, int tilesX) {
  const int bid  = blockIdx.x;
  const int b    = bid & 7;            // batch -> XCD
  const int tile = bid >> 3;
  const int bx   = tile % tilesX;      // M-tile (256 rows)
  const int by   = tile / tilesX;      // N-tile (128 cols)
  const int m = route[b];
  const __hip_bfloat16* Ab = A   + (size_t)b * Mdim * Kdim;
  const __hip_bfloat16* Bt = Btb + (size_t)m * Ndim * Kdim;
  const float* bias = biasbase + (size_t)m * Ndim;
  const int r0 = bx * 256;
  const int n0 = by * 128;

  __shared__ alignas(16) __hip_bfloat16 As[2][2][128 * 64];  // 64 KB
  __shared__ alignas(16) __hip_bfloat16 Bs[2][2][64 * 64];   // 32 KB

  const int t = threadIdx.x;
  const int w = t >> 6, l = t & 63;
  const int wm = w >> 1;               // 0..1  M half (128 rows)
  const int wn = w & 1;                // 0..1  N half (64 cols)

  const int srow = t >> 3;                     // 0..31
  const int scol = (t & 7) ^ ((t >> 3) & 7);   // inverse-swizzled 16B chunk

// A-half: 128 rows x 64 K = 16 KB = 4 loads/thread (rows i*32 + srow)
#define STAGE_AH2(sb, ha, k0)                                                 \
  { _Pragma("unroll")                                                         \
    for (int i = 0; i < 4; ++i)                                               \
      async_copy16(Ab + (size_t)(r0 + (ha) * 128 + i * 32 + srow) * Kdim + (k0) + scol * 8, \
                   &As[sb][ha][(i * 256 + t) * 8]); }
// B-half: 64 rows x 64 K = 8 KB = 2 loads/thread
#define STAGE_BH2(sb, hb, k0)                                                 \
  { _Pragma("unroll")                                                         \
    for (int i = 0; i < 2; ++i)                                               \
      async_copy16(Bt + (size_t)(n0 + (hb) * 64 + i * 32 + srow) * Kdim + (k0) + scol * 8, \
                   &Bs[sb][hb][(i * 256 + t) * 8]); }

  const int lrow = l & 15, lq = l >> 4, lx = l & 7;

#define LOAD_A2(mh)                                                           \
  { _Pragma("unroll")                                                         \
    for (int i = 0; i < 4; ++i) {                                             \
      const int row = ((mh) * 4 + i) * 16 + lrow;                             \
      aF[i][0] = *reinterpret_cast<const bf16x8*>(&aH[(row * 8 + ((0 + lq) ^ lx)) * 8]); \
      aF[i][1] = *reinterpret_cast<const bf16x8*>(&aH[(row * 8 + ((4 + lq) ^ lx)) * 8]); \
    } }
#define LOAD_B2(nh)                                                           \
  { _Pragma("unroll")                                                         \
    for (int j = 0; j < 2; ++j) {                                             \
      const int row = ((nh) * 2 + j) * 16 + lrow;                             \
      bF[nh][j][0] = *reinterpret_cast<const bf16x8*>(&bH[(row * 8 + ((0 + lq) ^ lx)) * 8]); \
      bF[nh][j][1] = *reinterpret_cast<const bf16x8*>(&bH[(row * 8 + ((4 + lq) ^ lx)) * 8]); \
    } }
#define MFMA_Q2(mh, nh)                                                       \
  { __builtin_amdgcn_s_setprio(1);                                            \
    _Pragma("unroll")                                                         \
    for (int i = 0; i < 4; ++i)                                               \
      _Pragma("unroll")                                                       \
      for (int j = 0; j < 2; ++j) {                                           \
        acc[(mh) * 4 + i][(nh) * 2 + j] = __builtin_amdgcn_mfma_f32_16x16x32_bf16( \
            aF[i][0], bF[nh][j][0], acc[(mh) * 4 + i][(nh) * 2 + j], 0, 0, 0);\
        acc[(mh) * 4 + i][(nh) * 2 + j] = __builtin_amdgcn_mfma_f32_16x16x32_bf16( \
            aF[i][1], bF[nh][j][1], acc[(mh) * 4 + i][(nh) * 2 + j], 0, 0, 0);\
      }                                                                       \
    __builtin_amdgcn_s_setprio(0); }
#define BARSCHED  { __builtin_amdgcn_s_barrier(); __builtin_amdgcn_sched_barrier(0); }

  f32x4 acc[8][4] = {};
  const int nt = Kdim >> 6;            // 32

  // prologue: tile 0 fully (12 ops), then B0(1)[2], A0(1)[4] as NEWEST 6
  STAGE_AH2(0, 0, 0)
  STAGE_AH2(0, 1, 0)
  STAGE_BH2(0, 0, 0)
  STAGE_BH2(0, 1, 0)
  if (nt > 1) { STAGE_BH2(1, 0, 64) STAGE_AH2(1, 0, 64) }

  for (int kt = 0; kt < nt; ++kt) {
    const int s = kt & 1;
    if (kt == nt - 1) { asm volatile("s_waitcnt vmcnt(0)" ::: "memory"); }
    else              { asm volatile("s_waitcnt vmcnt(6)" ::: "memory"); }
    BARSCHED

    const __hip_bfloat16* aH = As[s][wm];
    const __hip_bfloat16* bH = Bs[s][wn];
    bf16x8 aF[4][2], bF[2][2][2];

    // ph0: {read A0+B0; stage A1(kt+1)->opp; Q00} -> barrier
    LOAD_A2(0)
    LOAD_B2(0)
    if (kt + 1 < nt) STAGE_AH2(s ^ 1, 1, (kt + 1) * 64)
    MFMA_Q2(0, 0)
    BARSCHED

    // ph1: {read B1; stage B1(kt+1)->opp; Q01} -> barrier
    LOAD_B2(1)
    if (kt + 1 < nt) STAGE_BH2(s ^ 1, 1, (kt + 1) * 64)
    MFMA_Q2(0, 1)
    BARSCHED

    // ph2: {read A1; stage B0(kt+2)->cur (B reads done at ph1 bar); Q10} -> barrier
    LOAD_A2(1)
    if (kt + 2 < nt) STAGE_BH2(s, 0, (kt + 2) * 64)
    MFMA_Q2(1, 0)
    BARSCHED

    // ph3: {stage A0(kt+2)->cur (A reads done at ph2 bar); Q11}; loop-top bar
    if (kt + 2 < nt) STAGE_AH2(s, 0, (kt + 2) * 64)
    MFMA_Q2(1, 1)
  }
#undef STAGE_AH2
#undef STAGE_BH2
#undef LOAD_A2
#undef LOAD_B2
#undef MFMA_Q2
#undef BARSCHED

  // epilogue: f32 out + bias.  C/D layout col=lane&15, row=(lane>>4)*4+j
  float* out = outb + (size_t)b * Mdim * Ndim;
#pragma unroll
  for (int mb = 0; mb < 8; ++mb) {
    const int row = r0 + wm * 128 + mb * 16 + lq * 4;
#pragma unroll
    for (int nb = 0; nb < 4; ++nb) {
      const int col = n0 + wn * 64 + nb * 16 + lrow;
      const float bv = bias[col];
#pragma unroll
      for (int j = 0; j < 4; ++j)
        out[(size_t)(row + j) * Ndim + col] = acc[mb][nb][j] + bv;
    }
  }
}

// ---------------------------------------------------------------------------
extern "C" void kernel_launch(void* const* d_in, const int* in_sizes, int n_in,
                              void* d_out, int out_size, void* d_ws, size_t ws_size,
                              hipStream_t stream) {
  const float* x      = (const float*)d_in[0];
  const float* cond   = (const float*)d_in[1];
  const int*   route  = (const int*)d_in[2];
  const float* W_cond = (const float*)d_in[3];
  const float* b_cond = (const float*)d_in[4];
  const float* W1     = (const float*)d_in[5];
  const float* b1     = (const float*)d_in[6];
  const float* W2     = (const float*)d_in[7];
  const float* b2     = (const float*)d_in[8];
  float* out = (float*)d_out;

  // workspace layout (bytes)
  const size_t SS_OFF   = 0;
  const size_t XMOD_OFF = 32768;
  const size_t W1T_OFF  = XMOD_OFF + (size_t)BATCH * NTOK * DDIM * 2;
  const size_t W2T_OFF  = W1T_OFF + (size_t)NEXP * DDIM * DFFDIM * 2;
  const size_t H_OFF    = W2T_OFF + (size_t)NEXP * DFFDIM * DDIM * 2;
  const size_t NEED     = H_OFF + (size_t)BATCH * NTOK * DFFDIM * 2;
  if (ws_size < NEED) return;

  char* ws = (char*)d_ws;
  float* ss            = (float*)(ws + SS_OFF);
  __hip_bfloat16* xmod = (__hip_bfloat16*)(ws + XMOD_OFF);
  __hip_bfloat16* w1t  = (__hip_bfloat16*)(ws + W1T_OFF);
  __hip_bfloat16* w2t  = (__hip_bfloat16*)(ws + W2T_OFF);
  __hip_bfloat16* h    = (__hip_bfloat16*)(ws + H_OFF);

  // 1) cond modulation
  mod_kernel<<<dim3(2 * DDIM / 64, BATCH), 256, 0, stream>>>(cond, route, W_cond, b_cond, ss);

  // 2) FiLM -> bf16
  {
    const size_t groups = (size_t)BATCH * NTOK * DDIM / 4;
    film_kernel<<<(unsigned)(groups / 256), 256, 0, stream>>>(x, ss, xmod);
  }

  // 3) weight transpose+convert (routed experts only)
  transpose_cvt<<<dim3(DFFDIM / 32, DDIM / 32, NEXP), dim3(32, 8), 0, stream>>>(W1, w1t, DDIM, DFFDIM, route);
  transpose_cvt<<<dim3(DDIM / 32, DFFDIM / 32, NEXP), dim3(32, 8), 0, stream>>>(W2, w2t, DFFDIM, DDIM, route);

  // 4) GEMM1 (R12 control): grid 8*8*8 = 512 blocks
  gemm_8ph<0><<<(NTOK / 256) * (DFFDIM / 256) * BATCH, 512, 0, stream>>>(
      xmod, w1t, b1, h, route, NTOK, DFFDIM, DDIM, NTOK / 256);

  // 5) GEMM2 (4-barrier 8-phase, 4 waves): grid 8*4*8 = 256 blocks = 1/CU
  gemm2_8ph4w<<<(NTOK / 256) * (DDIM / 128) * BATCH, 256, 0, stream>>>(
      h, w2t, b2, out, route, NTOK, DDIM, DFFDIM, NTOK / 256);
}

// Round 14
// 133.629 us; speedup vs baseline: 1.0380x; 1.0380x over previous
//
#include <hip/hip_runtime.h>
#include <hip/hip_bf16.h>
#include <cstdint>
#include <cstddef>

// Problem dims (fixed by the reference)
#define NEXP   8
#define BATCH  8
#define NTOK   2048
#define DDIM   512
#define DFFDIM 2048
#define DCOND  512

typedef float  f32x4  __attribute__((ext_vector_type(4)));
typedef float  f32x4v __attribute__((ext_vector_type(4)));
typedef __bf16 bf16x8 __attribute__((ext_vector_type(8)));
typedef unsigned short ushort8v __attribute__((ext_vector_type(8)));

using as1_cvoid = __attribute__((address_space(1))) const void;
using as3_void  = __attribute__((address_space(3))) void;

__device__ __forceinline__ void async_copy16(const void* g, void* l) {
  __builtin_amdgcn_global_load_lds((as1_cvoid*)g, (as3_void*)l, 16, 0, 0);
}

__device__ __forceinline__ unsigned short f2bf_bits(float f) {
  __hip_bfloat16 h = __float2bfloat16(f);
  return *reinterpret_cast<unsigned short*>(&h);
}

// fast tanh-approx gelu: 0.5v(1+tanh(z)) == v * sigmoid(2z)
__device__ __forceinline__ float gelu_fast(float v) {
  float y = v * fmaf(0.0713548162726f, v * v, 1.5957691216057f);
  float e = exp2f(-1.44269504089f * y);
  return v * __builtin_amdgcn_rcpf(1.0f + e);
}

// ---------------------------------------------------------------------------
// 1) scale/shift = cond[b] @ W_cond[route[b]] + b_cond[route[b]] -> ss[B][1024]
// ---------------------------------------------------------------------------
__global__ void mod_kernel(const float* __restrict__ cond,
                           const int* __restrict__ route,
                           const float* __restrict__ W_cond,
                           const float* __restrict__ b_cond,
                           float* __restrict__ ss) {
  const int b = blockIdx.y;
  const int m = route[b];
  const int tj = threadIdx.x & 63;
  const int cq = threadIdx.x >> 6;            // 0..3
  const int j = blockIdx.x * 64 + tj;
  const float* wc = W_cond + (size_t)m * DCOND * (2 * DDIM);
  const float* cb = cond + (size_t)b * DCOND;
  float acc = 0.f;
#pragma unroll 4
  for (int c = cq * 128; c < cq * 128 + 128; ++c)
    acc += cb[c] * wc[(size_t)c * (2 * DDIM) + j];
  __shared__ float red[4][64];
  red[cq][tj] = acc;
  __syncthreads();
  if (cq == 0) {
    float v = red[0][tj] + red[1][tj] + red[2][tj] + red[3][tj];
    ss[(size_t)b * (2 * DDIM) + j] = v + b_cond[(size_t)m * (2 * DDIM) + j];
  }
}

// ---------------------------------------------------------------------------
// 2) x_mod = bf16( x * (1+scale) + shift )   [B][N][D] bf16
// ---------------------------------------------------------------------------
__global__ void film_kernel(const float* __restrict__ x,
                            const float* __restrict__ ss,
                            __hip_bfloat16* __restrict__ xmod) {
  const size_t idx = (size_t)blockIdx.x * blockDim.x + threadIdx.x;
  const int d4 = (int)(idx & (DDIM / 4 - 1));
  const int b  = (int)(idx >> 18);
  const float4 xv = reinterpret_cast<const float4*>(x)[idx];
  const float4 sc = reinterpret_cast<const float4*>(ss + (size_t)b * 1024)[d4];
  const float4 sh = reinterpret_cast<const float4*>(ss + (size_t)b * 1024 + DDIM)[d4];
  float r0 = xv.x * (1.f + sc.x) + sh.x;
  float r1 = xv.y * (1.f + sc.y) + sh.y;
  float r2 = xv.z * (1.f + sc.z) + sh.z;
  float r3 = xv.w * (1.f + sc.w) + sh.w;
  ushort4 ov;
  ov.x = f2bf_bits(r0); ov.y = f2bf_bits(r1);
  ov.z = f2bf_bits(r2); ov.w = f2bf_bits(r3);
  reinterpret_cast<ushort4*>(xmod)[idx] = ov;
}

// ---------------------------------------------------------------------------
// 3) transpose + f32->bf16:  in [M][L][R] f32  ->  out [M][R][L] bf16
// ---------------------------------------------------------------------------
__global__ void transpose_cvt(const float* __restrict__ in,
                              __hip_bfloat16* __restrict__ outp,
                              int L, int R,
                              const int* __restrict__ route) {
  const int mi = blockIdx.z;
  bool used = false;
#pragma unroll
  for (int b = 0; b < BATCH; ++b) used |= (route[b] == mi);
  if (!used) return;

  __shared__ float tile[32][33];
  const float* inm = in + (size_t)mi * L * R;
  __hip_bfloat16* outm = outp + (size_t)mi * L * R;
  const int r0 = blockIdx.x * 32, l0 = blockIdx.y * 32;
  const int tx = threadIdx.x, ty = threadIdx.y;
#pragma unroll
  for (int i = 0; i < 32; i += 8)
    tile[ty + i][tx] = inm[(size_t)(l0 + ty + i) * R + r0 + tx];
  __syncthreads();
#pragma unroll
  for (int i = 0; i < 32; i += 8)
    outm[(size_t)(r0 + ty + i) * L + l0 + tx] = __float2bfloat16(tile[tx][ty + i]);
}

// ---------------------------------------------------------------------------
// 4a) 4-BARRIER 8-PHASE GEMM1 (R12 K-loop unchanged) + LDS-BOUNCE EPILOGUE:
//     the old epilogue did 128 scalar 2B stores/thread (32B coalesced
//     segments, ~1024 wave-stores/block, est 15-30% of block time).  New:
//     per wave, per 16x64 C-subtile: scatter gelu(acc+bias) f32 into a
//     private LDS slice (stride 68 floats -> <=2-way banks), lgkmcnt(0)+
//     sched_barrier (rule 18), gather 16 f32/lane row-wise, convert bf16,
//     2x16B stores (lanes 0-3 = 64B contiguous).  16 stores/thread.
// ---------------------------------------------------------------------------
template <int EPI>
__global__ __launch_bounds__(512, 1) void gemm_8ph(
    const __hip_bfloat16* __restrict__ A,
    const __hip_bfloat16* __restrict__ Btb,
    const float* __restrict__ biasbase,
    void* __restrict__ outbase,
    const int* __restrict__ route,
    int Mdim, int Ndim, int Kdim, int tilesX) {
  const int bid  = blockIdx.x;
  const int b    = bid & 7;            // batch -> XCD
  const int tile = bid >> 3;
  const int bx   = tile % tilesX;
  const int by   = tile / tilesX;
  const int m = route[b];
  const __hip_bfloat16* Ab = A   + (size_t)b * Mdim * Kdim;
  const __hip_bfloat16* Bt = Btb + (size_t)m * Ndim * Kdim;
  const float* bias = biasbase + (size_t)m * Ndim;
  const int r0 = bx * 256;
  const int n0 = by * 256;

  __shared__ alignas(16) __hip_bfloat16 As[2][2][128 * 64];  // 64 KB
  __shared__ alignas(16) __hip_bfloat16 Bs[2][2][128 * 64];  // 64 KB

  const int t = threadIdx.x;
  const int w = t >> 6, l = t & 63;
  const int wm = w >> 2;               // 0..1  (M half, 128 rows)
  const int wn = w & 3;                // 0..3  (N quarter, 64 cols)

  const int srow = t >> 3;                     // 0..63
  const int scol = (t & 7) ^ ((t >> 3) & 7);   // inverse-swizzled 16B chunk

#define STAGE_AH(sb, ha, k0)                                                  \
  { async_copy16(Ab + (size_t)(r0 + (ha) * 128 + srow) * Kdim + (k0) + scol * 8, \
                 &As[sb][ha][(size_t)t * 8]);                                 \
    async_copy16(Ab + (size_t)(r0 + (ha) * 128 + 64 + srow) * Kdim + (k0) + scol * 8, \
                 &As[sb][ha][(size_t)(512 + t) * 8]); }
#define STAGE_BH(sb, hb, k0)                                                  \
  { async_copy16(Bt + (size_t)(n0 + (hb) * 128 + srow) * Kdim + (k0) + scol * 8, \
                 &Bs[sb][hb][(size_t)t * 8]);                                 \
    async_copy16(Bt + (size_t)(n0 + (hb) * 128 + 64 + srow) * Kdim + (k0) + scol * 8, \
                 &Bs[sb][hb][(size_t)(512 + t) * 8]); }

  const int lrow = l & 15, lq = l >> 4, lx = l & 7;

#define LOAD_A(mh)                                                            \
  { _Pragma("unroll")                                                         \
    for (int i = 0; i < 4; ++i) {                                             \
      const int row = ((mh) * 4 + i) * 16 + lrow;                             \
      aF[i][0] = *reinterpret_cast<const bf16x8*>(&aH[(row * 8 + ((0 + lq) ^ lx)) * 8]); \
      aF[i][1] = *reinterpret_cast<const bf16x8*>(&aH[(row * 8 + ((4 + lq) ^ lx)) * 8]); \
    } }
#define LOAD_B(nh)                                                            \
  { _Pragma("unroll")                                                         \
    for (int j = 0; j < 2; ++j) {                                             \
      const int row = (wn & 1) * 64 + ((nh) * 2 + j) * 16 + lrow;             \
      bF[nh][j][0] = *reinterpret_cast<const bf16x8*>(&bH[(row * 8 + ((0 + lq) ^ lx)) * 8]); \
      bF[nh][j][1] = *reinterpret_cast<const bf16x8*>(&bH[(row * 8 + ((4 + lq) ^ lx)) * 8]); \
    } }
#define MFMA_Q(mh, nh)                                                        \
  { __builtin_amdgcn_s_setprio(1);                                            \
    _Pragma("unroll")                                                         \
    for (int i = 0; i < 4; ++i)                                               \
      _Pragma("unroll")                                                       \
      for (int j = 0; j < 2; ++j) {                                           \
        acc[(mh) * 4 + i][(nh) * 2 + j] = __builtin_amdgcn_mfma_f32_16x16x32_bf16( \
            aF[i][0], bF[nh][j][0], acc[(mh) * 4 + i][(nh) * 2 + j], 0, 0, 0);\
        acc[(mh) * 4 + i][(nh) * 2 + j] = __builtin_amdgcn_mfma_f32_16x16x32_bf16( \
            aF[i][1], bF[nh][j][1], acc[(mh) * 4 + i][(nh) * 2 + j], 0, 0, 0);\
      }                                                                       \
    __builtin_amdgcn_s_setprio(0); }
#define BARSCHED  { __builtin_amdgcn_s_barrier(); __builtin_amdgcn_sched_barrier(0); }

  f32x4 acc[8][4] = {};
  const int nt = Kdim >> 6;

  STAGE_BH(0, 0, 0)
  STAGE_AH(0, 0, 0)
  STAGE_AH(0, 1, 0)
  STAGE_BH(0, 1, 0)
  if (nt > 1) { STAGE_BH(1, 0, 64) STAGE_AH(1, 0, 64) }

  for (int kt = 0; kt < nt; ++kt) {
    const int s = kt & 1;
    if (kt == nt - 1) { asm volatile("s_waitcnt vmcnt(0)" ::: "memory"); }
    else              { asm volatile("s_waitcnt vmcnt(4)" ::: "memory"); }
    BARSCHED

    const __hip_bfloat16* aH = As[s][wm];
    const __hip_bfloat16* bH = Bs[s][wn >> 1];
    bf16x8 aF[4][2], bF[2][2][2];

    LOAD_A(0)
    LOAD_B(0)
    if (kt + 1 < nt) STAGE_AH(s ^ 1, 1, (kt + 1) * 64)
    MFMA_Q(0, 0)
    BARSCHED

    LOAD_B(1)
    if (kt + 1 < nt) STAGE_BH(s ^ 1, 1, (kt + 1) * 64)
    MFMA_Q(0, 1)
    BARSCHED

    LOAD_A(1)
    if (kt + 2 < nt) STAGE_BH(s, 0, (kt + 2) * 64)
    MFMA_Q(1, 0)
    BARSCHED

    if (kt + 2 < nt) STAGE_AH(s, 0, (kt + 2) * 64)
    MFMA_Q(1, 1)
  }
#undef STAGE_AH
#undef STAGE_BH
#undef LOAD_A
#undef LOAD_B
#undef MFMA_Q
#undef BARSCHED

  // ---- LDS-bounce epilogue ----
  __builtin_amdgcn_s_barrier();          // all last-tile LDS reads complete
  __builtin_amdgcn_sched_barrier(0);     // nothing below hoists above

  if (EPI == 0) {
    __hip_bfloat16* out = (__hip_bfloat16*)outbase + (size_t)b * Mdim * Ndim;
    // per-wave private f32 slice in the As region: 16 rows x stride 68
    float* eb = reinterpret_cast<float*>(&As[0][0][0]) + w * 1104;
    const int rr = l >> 2, cc = l & 3;
#pragma unroll
    for (int mb = 0; mb < 8; ++mb) {
      // scatter: MFMA layout -> LDS rows (gelu+bias applied here)
#pragma unroll
      for (int nb = 0; nb < 4; ++nb) {
        const float bv = bias[n0 + wn * 64 + nb * 16 + lrow];
#pragma unroll
        for (int j = 0; j < 4; ++j)
          eb[(lq * 4 + j) * 68 + nb * 16 + lrow] = gelu_fast(acc[mb][nb][j] + bv);
      }
      asm volatile("s_waitcnt lgkmcnt(0)" ::: "memory");
      __builtin_amdgcn_sched_barrier(0);
      // gather: lane -> (row rr, col-chunk cc*16), 16 f32 contiguous
      f32x4v v0 = *reinterpret_cast<const f32x4v*>(&eb[rr * 68 + cc * 16 + 0]);
      f32x4v v1 = *reinterpret_cast<const f32x4v*>(&eb[rr * 68 + cc * 16 + 4]);
      f32x4v v2 = *reinterpret_cast<const f32x4v*>(&eb[rr * 68 + cc * 16 + 8]);
      f32x4v v3 = *reinterpret_cast<const f32x4v*>(&eb[rr * 68 + cc * 16 + 12]);
      asm volatile("s_waitcnt lgkmcnt(0)" ::: "memory");
      __builtin_amdgcn_sched_barrier(0);
      ushort8v o0, o1;
#pragma unroll
      for (int k = 0; k < 4; ++k) {
        o0[k]     = f2bf_bits(v0[k]);
        o0[4 + k] = f2bf_bits(v1[k]);
        o1[k]     = f2bf_bits(v2[k]);
        o1[4 + k] = f2bf_bits(v3[k]);
      }
      const size_t row = (size_t)(r0 + wm * 128 + mb * 16 + rr);
      const int colb = n0 + wn * 64 + cc * 16;
      *reinterpret_cast<ushort8v*>(&out[row * Ndim + colb])     = o0;
      *reinterpret_cast<ushort8v*>(&out[row * Ndim + colb + 8]) = o1;
      // slice reuse across mb iterations: same-wave lgkmcnt(0) above orders
      // this mb's reads before next mb's writes (no cross-wave sharing).
    }
  } else {
    float* out = (float*)outbase + (size_t)b * Mdim * Ndim;
#pragma unroll
    for (int mb = 0; mb < 8; ++mb) {
      const int row = r0 + wm * 128 + mb * 16 + lq * 4;
#pragma unroll
      for (int nb = 0; nb < 4; ++nb) {
        const int col = n0 + wn * 64 + nb * 16 + lrow;
        const float bv = bias[col];
#pragma unroll
        for (int j = 0; j < 4; ++j)
          out[(size_t)(row + j) * Ndim + col] = acc[mb][nb][j] + bv;
      }
    }
  }
}

// ---------------------------------------------------------------------------
// 4b) GEMM2 — R6/R12-proven gemm_db2 (BM=BN=128, BK=64), control.
// ---------------------------------------------------------------------------
template <int EPI>
__global__ __launch_bounds__(256, 2) void gemm_db2(
    const __hip_bfloat16* __restrict__ Abase,
    const __hip_bfloat16* __restrict__ Btbase,
    const float* __restrict__ biasbase,
    void* __restrict__ outbase,
    const int* __restrict__ route,
    int Mdim, int Ndim, int Kdim, int tilesX) {
  const int bid  = blockIdx.x;
  const int b    = bid & 7;
  const int tile = bid >> 3;
  const int bx   = tile % tilesX;
  const int by   = tile / tilesX;
  const int m = route[b];
  const __hip_bfloat16* A  = Abase  + (size_t)b * Mdim * Kdim;
  const __hip_bfloat16* Bt = Btbase + (size_t)m * Ndim * Kdim;
  const float* bias = biasbase + (size_t)m * Ndim;
  const int r0 = bx * 128;
  const int n0 = by * 128;

  __shared__ alignas(16) __hip_bfloat16 As[2][128 * 64];
  __shared__ alignas(16) __hip_bfloat16 Bs[2][128 * 64];

  const int t = threadIdx.x;
  const int w = t >> 6, l = t & 63;
  const int wr = w >> 1, wc = w & 1;

  const int srow = t >> 3;
  const int scol = (t & 7) ^ ((t >> 3) & 7);

#define STAGE(s_, k0)                                                         \
  { _Pragma("unroll")                                                         \
    for (int i = 0; i < 4; ++i)                                               \
      async_copy16(A + (size_t)(r0 + i * 32 + srow) * Kdim + (k0) + scol * 8, \
                   &As[s_][(i * 256 + t) * 8]);                               \
    _Pragma("unroll")                                                         \
    for (int i = 0; i < 4; ++i)                                               \
      async_copy16(Bt + (size_t)(n0 + i * 32 + srow) * Kdim + (k0) + scol * 8,\
                   &Bs[s_][(i * 256 + t) * 8]); }

  const int lrow = l & 15, lq = l >> 4, lx = l & 7;
  f32x4 acc[4][4] = {};
  const int nt = Kdim >> 6;

  STAGE(0, 0)

  for (int kt = 0; kt < nt; ++kt) {
    const int s = kt & 1;
    if (kt + 1 < nt) {
      STAGE(s ^ 1, (kt + 1) * 64)
      asm volatile("s_waitcnt vmcnt(8)" ::: "memory");
    } else {
      asm volatile("s_waitcnt vmcnt(0)" ::: "memory");
    }
    __builtin_amdgcn_s_barrier();
    __builtin_amdgcn_sched_barrier(0);

    const __hip_bfloat16* as_ = As[s];
    const __hip_bfloat16* bs_ = Bs[s];
    bf16x8 af[4][2], bfr[4][2];
#pragma unroll
    for (int mb = 0; mb < 4; ++mb) {
      const int row = wr * 64 + mb * 16 + lrow;
      af[mb][0] = *reinterpret_cast<const bf16x8*>(&as_[(row * 8 + ((0 + lq) ^ lx)) * 8]);
      af[mb][1] = *reinterpret_cast<const bf16x8*>(&as_[(row * 8 + ((4 + lq) ^ lx)) * 8]);
    }
#pragma unroll
    for (int nb = 0; nb < 4; ++nb) {
      const int row = wc * 64 + nb * 16 + lrow;
      bfr[nb][0] = *reinterpret_cast<const bf16x8*>(&bs_[(row * 8 + ((0 + lq) ^ lx)) * 8]);
      bfr[nb][1] = *reinterpret_cast<const bf16x8*>(&bs_[(row * 8 + ((4 + lq) ^ lx)) * 8]);
    }
#pragma unroll
    for (int mb = 0; mb < 4; ++mb)
#pragma unroll
      for (int nb = 0; nb < 4; ++nb) {
        acc[mb][nb] = __builtin_amdgcn_mfma_f32_16x16x32_bf16(
            af[mb][0], bfr[nb][0], acc[mb][nb], 0, 0, 0);
        acc[mb][nb] = __builtin_amdgcn_mfma_f32_16x16x32_bf16(
            af[mb][1], bfr[nb][1], acc[mb][nb], 0, 0, 0);
      }

    __builtin_amdgcn_sched_barrier(0);
    __builtin_amdgcn_s_barrier();
  }
#undef STAGE

  if (EPI == 0) {
    __hip_bfloat16* out = (__hip_bfloat16*)outbase + (size_t)b * Mdim * Ndim;
#pragma unroll
    for (int mb = 0; mb < 4; ++mb) {
      const int row = r0 + wr * 64 + mb * 16 + lq * 4;
#pragma unroll
      for (int nb = 0; nb < 4; ++nb) {
        const int col = n0 + wc * 64 + nb * 16 + lrow;
        const float bv = bias[col];
#pragma unroll
        for (int j = 0; j < 4; ++j) {
          float g = gelu_fast(acc[mb][nb][j] + bv);
          out[(size_t)(row + j) * Ndim + col] = __float2bfloat16(g);
        }
      }
    }
  } else {
    float* out = (float*)outbase + (size_t)b * Mdim * Ndim;
#pragma unroll
    for (int mb = 0; mb < 4; ++mb) {
      const int row = r0 + wr * 64 + mb * 16 + lq * 4;
#pragma unroll
      for (int nb = 0; nb < 4; ++nb) {
        const int col = n0 + wc * 64 + nb * 16 + lrow;
        const float bv = bias[col];
#pragma unroll
        for (int j = 0; j < 4; ++j)
          out[(size_t)(row + j) * Ndim + col] = acc[mb][nb][j] + bv;
      }
    }
  }
}

// ---------------------------------------------------------------------------
extern "C" void kernel_launch(void* const* d_in, const int* in_sizes, int n_in,
                              void* d_out, int out_size, void* d_ws, size_t ws_size,
                              hipStream_t stream) {
  const float* x      = (const float*)d_in[0];
  const float* cond   = (const float*)d_in[1];
  const int*   route  = (const int*)d_in[2];
  const float* W_cond = (const float*)d_in[3];
  const float* b_cond = (const float*)d_in[4];
  const float* W1     = (const float*)d_in[5];
  const float* b1     = (const float*)d_in[6];
  const float* W2     = (const float*)d_in[7];
  const float* b2     = (const float*)d_in[8];
  float* out = (float*)d_out;

  // workspace layout (bytes)
  const size_t SS_OFF   = 0;
  const size_t XMOD_OFF = 32768;
  const size_t W1T_OFF  = XMOD_OFF + (size_t)BATCH * NTOK * DDIM * 2;
  const size_t W2T_OFF  = W1T_OFF + (size_t)NEXP * DDIM * DFFDIM * 2;
  const size_t H_OFF    = W2T_OFF + (size_t)NEXP * DFFDIM * DDIM * 2;
  const size_t NEED     = H_OFF + (size_t)BATCH * NTOK * DFFDIM * 2;
  if (ws_size < NEED) return;

  char* ws = (char*)d_ws;
  float* ss            = (float*)(ws + SS_OFF);
  __hip_bfloat16* xmod = (__hip_bfloat16*)(ws + XMOD_OFF);
  __hip_bfloat16* w1t  = (__hip_bfloat16*)(ws + W1T_OFF);
  __hip_bfloat16* w2t  = (__hip_bfloat16*)(ws + W2T_OFF);
  __hip_bfloat16* h    = (__hip_bfloat16*)(ws + H_OFF);

  // 1) cond modulation
  mod_kernel<<<dim3(2 * DDIM / 64, BATCH), 256, 0, stream>>>(cond, route, W_cond, b_cond, ss);

  // 2) FiLM -> bf16
  {
    const size_t groups = (size_t)BATCH * NTOK * DDIM / 4;
    film_kernel<<<(unsigned)(groups / 256), 256, 0, stream>>>(x, ss, xmod);
  }

  // 3) weight transpose+convert (routed experts only)
  transpose_cvt<<<dim3(DFFDIM / 32, DDIM / 32, NEXP), dim3(32, 8), 0, stream>>>(W1, w1t, DDIM, DFFDIM, route);
  transpose_cvt<<<dim3(DDIM / 32, DFFDIM / 32, NEXP), dim3(32, 8), 0, stream>>>(W2, w2t, DFFDIM, DDIM, route);

  // 4) GEMM1 (8-phase + LDS-bounce epilogue): grid 8*8*8 = 512 blocks
  gemm_8ph<0><<<(NTOK / 256) * (DFFDIM / 256) * BATCH, 512, 0, stream>>>(
      xmod, w1t, b1, h, route, NTOK, DFFDIM, DDIM, NTOK / 256);

  // 5) GEMM2 (db2 control, reverted): grid 16*4*8 = 512 blocks
  gemm_db2<1><<<(NTOK / 128) * (DDIM / 128) * BATCH, 256, 0, stream>>>(
      h, w2t, b2, out, route, NTOK, DDIM, DFFDIM, NTOK / 128);
}

// Round 15
// 128.219 us; speedup vs baseline: 1.0818x; 1.0422x over previous
//
#include <hip/hip_runtime.h>
#include <hip/hip_bf16.h>
#include <cstdint>
#include <cstddef>

// Problem dims (fixed by the reference)
#define NEXP   8
#define BATCH  8
#define NTOK   2048
#define DDIM   512
#define DFFDIM 2048
#define DCOND  512

typedef float  f32x4  __attribute__((ext_vector_type(4)));
typedef __bf16 bf16x8 __attribute__((ext_vector_type(8)));
typedef unsigned short ushort8v __attribute__((ext_vector_type(8)));

using as1_cvoid = __attribute__((address_space(1))) const void;
using as3_void  = __attribute__((address_space(3))) void;

__device__ __forceinline__ void async_copy16(const void* g, void* l) {
  __builtin_amdgcn_global_load_lds((as1_cvoid*)g, (as3_void*)l, 16, 0, 0);
}

__device__ __forceinline__ unsigned short f2bf_bits(float f) {
  __hip_bfloat16 h = __float2bfloat16(f);
  return *reinterpret_cast<unsigned short*>(&h);
}

// fast tanh-approx gelu: 0.5v(1+tanh(z)) == v * sigmoid(2z)
__device__ __forceinline__ float gelu_fast(float v) {
  float y = v * fmaf(0.0713548162726f, v * v, 1.5957691216057f);
  float e = exp2f(-1.44269504089f * y);
  return v * __builtin_amdgcn_rcpf(1.0f + e);
}

// ---------------------------------------------------------------------------
// 1) scale/shift = cond[b] @ W_cond[route[b]] + b_cond[route[b]] -> ss[B][1024]
// ---------------------------------------------------------------------------
__global__ void mod_kernel(const float* __restrict__ cond,
                           const int* __restrict__ route,
                           const float* __restrict__ W_cond,
                           const float* __restrict__ b_cond,
                           float* __restrict__ ss) {
  const int b = blockIdx.y;
  const int m = route[b];
  const int tj = threadIdx.x & 63;
  const int cq = threadIdx.x >> 6;            // 0..3
  const int j = blockIdx.x * 64 + tj;
  const float* wc = W_cond + (size_t)m * DCOND * (2 * DDIM);
  const float* cb = cond + (size_t)b * DCOND;
  float acc = 0.f;
#pragma unroll 4
  for (int c = cq * 128; c < cq * 128 + 128; ++c)
    acc += cb[c] * wc[(size_t)c * (2 * DDIM) + j];
  __shared__ float red[4][64];
  red[cq][tj] = acc;
  __syncthreads();
  if (cq == 0) {
    float v = red[0][tj] + red[1][tj] + red[2][tj] + red[3][tj];
    ss[(size_t)b * (2 * DDIM) + j] = v + b_cond[(size_t)m * (2 * DDIM) + j];
  }
}

// ---------------------------------------------------------------------------
// 2) x_mod = bf16( x * (1+scale) + shift )   [B][N][D] bf16  (8 elems/thread)
// ---------------------------------------------------------------------------
__global__ void film_kernel(const float* __restrict__ x,
                            const float* __restrict__ ss,
                            __hip_bfloat16* __restrict__ xmod) {
  const size_t idx = (size_t)blockIdx.x * blockDim.x + threadIdx.x; // 8-float group
  const int d8 = (int)(idx & (DDIM / 8 - 1));          // 0..63
  const int b  = (int)(idx >> 17);                      // / (N*D/8) = 2^17
  const float4 x0 = reinterpret_cast<const float4*>(x)[idx * 2];
  const float4 x1 = reinterpret_cast<const float4*>(x)[idx * 2 + 1];
  const float4 sc0 = reinterpret_cast<const float4*>(ss + (size_t)b * 1024)[d8 * 2];
  const float4 sc1 = reinterpret_cast<const float4*>(ss + (size_t)b * 1024)[d8 * 2 + 1];
  const float4 sh0 = reinterpret_cast<const float4*>(ss + (size_t)b * 1024 + DDIM)[d8 * 2];
  const float4 sh1 = reinterpret_cast<const float4*>(ss + (size_t)b * 1024 + DDIM)[d8 * 2 + 1];
  ushort8v ov;
  ov[0] = f2bf_bits(x0.x * (1.f + sc0.x) + sh0.x);
  ov[1] = f2bf_bits(x0.y * (1.f + sc0.y) + sh0.y);
  ov[2] = f2bf_bits(x0.z * (1.f + sc0.z) + sh0.z);
  ov[3] = f2bf_bits(x0.w * (1.f + sc0.w) + sh0.w);
  ov[4] = f2bf_bits(x1.x * (1.f + sc1.x) + sh1.x);
  ov[5] = f2bf_bits(x1.y * (1.f + sc1.y) + sh1.y);
  ov[6] = f2bf_bits(x1.z * (1.f + sc1.z) + sh1.z);
  ov[7] = f2bf_bits(x1.w * (1.f + sc1.w) + sh1.w);
  reinterpret_cast<ushort8v*>(xmod)[idx] = ov;
}

// ---------------------------------------------------------------------------
// 3) transpose + f32->bf16, 64x64 tiles (float4 reads, ushort4 writes):
//    in [M][L][R] f32  ->  out [M][R][L] bf16.  Skips unrouted experts.
// ---------------------------------------------------------------------------
__global__ void transpose_cvt(const float* __restrict__ in,
                              __hip_bfloat16* __restrict__ outp,
                              int L, int R,
                              const int* __restrict__ route) {
  const int mi = blockIdx.z;
  bool used = false;
#pragma unroll
  for (int b = 0; b < BATCH; ++b) used |= (route[b] == mi);
  if (!used) return;

  __shared__ float tile[64][65];
  const float* inm = in + (size_t)mi * L * R;
  __hip_bfloat16* outm = outp + (size_t)mi * L * R;
  const int r0 = blockIdx.x * 64, l0 = blockIdx.y * 64;
  const int tx = threadIdx.x & 15, ty = threadIdx.x >> 4;   // 16 x 16
#pragma unroll
  for (int i = 0; i < 4; ++i) {
    const int row = ty + i * 16;
    const float4 v = *reinterpret_cast<const float4*>(
        &inm[(size_t)(l0 + row) * R + r0 + tx * 4]);
    tile[row][tx * 4 + 0] = v.x;
    tile[row][tx * 4 + 1] = v.y;
    tile[row][tx * 4 + 2] = v.z;
    tile[row][tx * 4 + 3] = v.w;
  }
  __syncthreads();
#pragma unroll
  for (int i = 0; i < 4; ++i) {
    const int orow = ty + i * 16;          // output row = tile column orow
    ushort4 o;
    o.x = f2bf_bits(tile[tx * 4 + 0][orow]);
    o.y = f2bf_bits(tile[tx * 4 + 1][orow]);
    o.z = f2bf_bits(tile[tx * 4 + 2][orow]);
    o.w = f2bf_bits(tile[tx * 4 + 3][orow]);
    *reinterpret_cast<ushort4*>(&outm[(size_t)(r0 + orow) * L + l0 + tx * 4]) = o;
  }
}

// ---------------------------------------------------------------------------
// 4a) 4-BARRIER 8-PHASE GEMM1 (R12-proven, scalar epilogue): BM=BN=256,
//     BK=64, 512 threads = 8 waves (2M x 4N), wave-tile 128x64.
// ---------------------------------------------------------------------------
template <int EPI>
__global__ __launch_bounds__(512, 1) void gemm_8ph(
    const __hip_bfloat16* __restrict__ A,
    const __hip_bfloat16* __restrict__ Btb,
    const float* __restrict__ biasbase,
    void* __restrict__ outbase,
    const int* __restrict__ route,
    int Mdim, int Ndim, int Kdim, int tilesX) {
  const int bid  = blockIdx.x;
  const int b    = bid & 7;            // batch -> XCD
  const int tile = bid >> 3;
  const int bx   = tile % tilesX;
  const int by   = tile / tilesX;
  const int m = route[b];
  const __hip_bfloat16* Ab = A   + (size_t)b * Mdim * Kdim;
  const __hip_bfloat16* Bt = Btb + (size_t)m * Ndim * Kdim;
  const float* bias = biasbase + (size_t)m * Ndim;
  const int r0 = bx * 256;
  const int n0 = by * 256;

  __shared__ alignas(16) __hip_bfloat16 As[2][2][128 * 64];  // 64 KB
  __shared__ alignas(16) __hip_bfloat16 Bs[2][2][128 * 64];  // 64 KB

  const int t = threadIdx.x;
  const int w = t >> 6, l = t & 63;
  const int wm = w >> 2;               // 0..1  (M half, 128 rows)
  const int wn = w & 3;                // 0..3  (N quarter, 64 cols)

  const int srow = t >> 3;                     // 0..63
  const int scol = (t & 7) ^ ((t >> 3) & 7);   // inverse-swizzled 16B chunk

#define STAGE_AH(sb, ha, k0)                                                  \
  { async_copy16(Ab + (size_t)(r0 + (ha) * 128 + srow) * Kdim + (k0) + scol * 8, \
                 &As[sb][ha][(size_t)t * 8]);                                 \
    async_copy16(Ab + (size_t)(r0 + (ha) * 128 + 64 + srow) * Kdim + (k0) + scol * 8, \
                 &As[sb][ha][(size_t)(512 + t) * 8]); }
#define STAGE_BH(sb, hb, k0)                                                  \
  { async_copy16(Bt + (size_t)(n0 + (hb) * 128 + srow) * Kdim + (k0) + scol * 8, \
                 &Bs[sb][hb][(size_t)t * 8]);                                 \
    async_copy16(Bt + (size_t)(n0 + (hb) * 128 + 64 + srow) * Kdim + (k0) + scol * 8, \
                 &Bs[sb][hb][(size_t)(512 + t) * 8]); }

  const int lrow = l & 15, lq = l >> 4, lx = l & 7;

#define LOAD_A(mh)                                                            \
  { _Pragma("unroll")                                                         \
    for (int i = 0; i < 4; ++i) {                                             \
      const int row = ((mh) * 4 + i) * 16 + lrow;                             \
      aF[i][0] = *reinterpret_cast<const bf16x8*>(&aH[(row * 8 + ((0 + lq) ^ lx)) * 8]); \
      aF[i][1] = *reinterpret_cast<const bf16x8*>(&aH[(row * 8 + ((4 + lq) ^ lx)) * 8]); \
    } }
#define LOAD_B(nh)                                                            \
  { _Pragma("unroll")                                                         \
    for (int j = 0; j < 2; ++j) {                                             \
      const int row = (wn & 1) * 64 + ((nh) * 2 + j) * 16 + lrow;             \
      bF[nh][j][0] = *reinterpret_cast<const bf16x8*>(&bH[(row * 8 + ((0 + lq) ^ lx)) * 8]); \
      bF[nh][j][1] = *reinterpret_cast<const bf16x8*>(&bH[(row * 8 + ((4 + lq) ^ lx)) * 8]); \
    } }
#define MFMA_Q(mh, nh)                                                        \
  { __builtin_amdgcn_s_setprio(1);                                            \
    _Pragma("unroll")                                                         \
    for (int i = 0; i < 4; ++i)                                               \
      _Pragma("unroll")                                                       \
      for (int j = 0; j < 2; ++j) {                                           \
        acc[(mh) * 4 + i][(nh) * 2 + j] = __builtin_amdgcn_mfma_f32_16x16x32_bf16( \
            aF[i][0], bF[nh][j][0], acc[(mh) * 4 + i][(nh) * 2 + j], 0, 0, 0);\
        acc[(mh) * 4 + i][(nh) * 2 + j] = __builtin_amdgcn_mfma_f32_16x16x32_bf16( \
            aF[i][1], bF[nh][j][1], acc[(mh) * 4 + i][(nh) * 2 + j], 0, 0, 0);\
      }                                                                       \
    __builtin_amdgcn_s_setprio(0); }
#define BARSCHED  { __builtin_amdgcn_s_barrier(); __builtin_amdgcn_sched_barrier(0); }

  f32x4 acc[8][4] = {};
  const int nt = Kdim >> 6;

  STAGE_BH(0, 0, 0)
  STAGE_AH(0, 0, 0)
  STAGE_AH(0, 1, 0)
  STAGE_BH(0, 1, 0)
  if (nt > 1) { STAGE_BH(1, 0, 64) STAGE_AH(1, 0, 64) }

  for (int kt = 0; kt < nt; ++kt) {
    const int s = kt & 1;
    if (kt == nt - 1) { asm volatile("s_waitcnt vmcnt(0)" ::: "memory"); }
    else              { asm volatile("s_waitcnt vmcnt(4)" ::: "memory"); }
    BARSCHED

    const __hip_bfloat16* aH = As[s][wm];
    const __hip_bfloat16* bH = Bs[s][wn >> 1];
    bf16x8 aF[4][2], bF[2][2][2];

    LOAD_A(0)
    LOAD_B(0)
    if (kt + 1 < nt) STAGE_AH(s ^ 1, 1, (kt + 1) * 64)
    MFMA_Q(0, 0)
    BARSCHED

    LOAD_B(1)
    if (kt + 1 < nt) STAGE_BH(s ^ 1, 1, (kt + 1) * 64)
    MFMA_Q(0, 1)
    BARSCHED

    LOAD_A(1)
    if (kt + 2 < nt) STAGE_BH(s, 0, (kt + 2) * 64)
    MFMA_Q(1, 0)
    BARSCHED

    if (kt + 2 < nt) STAGE_AH(s, 0, (kt + 2) * 64)
    MFMA_Q(1, 1)
  }
#undef STAGE_AH
#undef STAGE_BH
#undef LOAD_A
#undef LOAD_B
#undef MFMA_Q
#undef BARSCHED

  if (EPI == 0) {
    __hip_bfloat16* out = (__hip_bfloat16*)outbase + (size_t)b * Mdim * Ndim;
#pragma unroll
    for (int mb = 0; mb < 8; ++mb) {
      const int row = r0 + wm * 128 + mb * 16 + lq * 4;
#pragma unroll
      for (int nb = 0; nb < 4; ++nb) {
        const int col = n0 + wn * 64 + nb * 16 + lrow;
        const float bv = bias[col];
#pragma unroll
        for (int j = 0; j < 4; ++j) {
          float g = gelu_fast(acc[mb][nb][j] + bv);
          out[(size_t)(row + j) * Ndim + col] = __float2bfloat16(g);
        }
      }
    }
  } else {
    float* out = (float*)outbase + (size_t)b * Mdim * Ndim;
#pragma unroll
    for (int mb = 0; mb < 8; ++mb) {
      const int row = r0 + wm * 128 + mb * 16 + lq * 4;
#pragma unroll
      for (int nb = 0; nb < 4; ++nb) {
        const int col = n0 + wn * 64 + nb * 16 + lrow;
        const float bv = bias[col];
#pragma unroll
        for (int j = 0; j < 4; ++j)
          out[(size_t)(row + j) * Ndim + col] = acc[mb][nb][j] + bv;
      }
    }
  }
}

// ---------------------------------------------------------------------------
// 4b) GEMM2 — R6/R12-proven gemm_db2 (BM=BN=128, BK=64), control.
// ---------------------------------------------------------------------------
template <int EPI>
__global__ __launch_bounds__(256, 2) void gemm_db2(
    const __hip_bfloat16* __restrict__ Abase,
    const __hip_bfloat16* __restrict__ Btbase,
    const float* __restrict__ biasbase,
    void* __restrict__ outbase,
    const int* __restrict__ route,
    int Mdim, int Ndim, int Kdim, int tilesX) {
  const int bid  = blockIdx.x;
  const int b    = bid & 7;
  const int tile = bid >> 3;
  const int bx   = tile % tilesX;
  const int by   = tile / tilesX;
  const int m = route[b];
  const __hip_bfloat16* A  = Abase  + (size_t)b * Mdim * Kdim;
  const __hip_bfloat16* Bt = Btbase + (size_t)m * Ndim * Kdim;
  const float* bias = biasbase + (size_t)m * Ndim;
  const int r0 = bx * 128;
  const int n0 = by * 128;

  __shared__ alignas(16) __hip_bfloat16 As[2][128 * 64];
  __shared__ alignas(16) __hip_bfloat16 Bs[2][128 * 64];

  const int t = threadIdx.x;
  const int w = t >> 6, l = t & 63;
  const int wr = w >> 1, wc = w & 1;

  const int srow = t >> 3;
  const int scol = (t & 7) ^ ((t >> 3) & 7);

#define STAGE(s_, k0)                                                         \
  { _Pragma("unroll")                                                         \
    for (int i = 0; i < 4; ++i)                                               \
      async_copy16(A + (size_t)(r0 + i * 32 + srow) * Kdim + (k0) + scol * 8, \
                   &As[s_][(i * 256 + t) * 8]);                               \
    _Pragma("unroll")                                                         \
    for (int i = 0; i < 4; ++i)                                               \
      async_copy16(Bt + (size_t)(n0 + i * 32 + srow) * Kdim + (k0) + scol * 8,\
                   &Bs[s_][(i * 256 + t) * 8]); }

  const int lrow = l & 15, lq = l >> 4, lx = l & 7;
  f32x4 acc[4][4] = {};
  const int nt = Kdim >> 6;

  STAGE(0, 0)

  for (int kt = 0; kt < nt; ++kt) {
    const int s = kt & 1;
    if (kt + 1 < nt) {
      STAGE(s ^ 1, (kt + 1) * 64)
      asm volatile("s_waitcnt vmcnt(8)" ::: "memory");
    } else {
      asm volatile("s_waitcnt vmcnt(0)" ::: "memory");
    }
    __builtin_amdgcn_s_barrier();
    __builtin_amdgcn_sched_barrier(0);

    const __hip_bfloat16* as_ = As[s];
    const __hip_bfloat16* bs_ = Bs[s];
    bf16x8 af[4][2], bfr[4][2];
#pragma unroll
    for (int mb = 0; mb < 4; ++mb) {
      const int row = wr * 64 + mb * 16 + lrow;
      af[mb][0] = *reinterpret_cast<const bf16x8*>(&as_[(row * 8 + ((0 + lq) ^ lx)) * 8]);
      af[mb][1] = *reinterpret_cast<const bf16x8*>(&as_[(row * 8 + ((4 + lq) ^ lx)) * 8]);
    }
#pragma unroll
    for (int nb = 0; nb < 4; ++nb) {
      const int row = wc * 64 + nb * 16 + lrow;
      bfr[nb][0] = *reinterpret_cast<const bf16x8*>(&bs_[(row * 8 + ((0 + lq) ^ lx)) * 8]);
      bfr[nb][1] = *reinterpret_cast<const bf16x8*>(&bs_[(row * 8 + ((4 + lq) ^ lx)) * 8]);
    }
#pragma unroll
    for (int mb = 0; mb < 4; ++mb)
#pragma unroll
      for (int nb = 0; nb < 4; ++nb) {
        acc[mb][nb] = __builtin_amdgcn_mfma_f32_16x16x32_bf16(
            af[mb][0], bfr[nb][0], acc[mb][nb], 0, 0, 0);
        acc[mb][nb] = __builtin_amdgcn_mfma_f32_16x16x32_bf16(
            af[mb][1], bfr[nb][1], acc[mb][nb], 0, 0, 0);
      }

    __builtin_amdgcn_sched_barrier(0);
    __builtin_amdgcn_s_barrier();
  }
#undef STAGE

  if (EPI == 0) {
    __hip_bfloat16* out = (__hip_bfloat16*)outbase + (size_t)b * Mdim * Ndim;
#pragma unroll
    for (int mb = 0; mb < 4; ++mb) {
      const int row = r0 + wr * 64 + mb * 16 + lq * 4;
#pragma unroll
      for (int nb = 0; nb < 4; ++nb) {
        const int col = n0 + wc * 64 + nb * 16 + lrow;
        const float bv = bias[col];
#pragma unroll
        for (int j = 0; j < 4; ++j) {
          float g = gelu_fast(acc[mb][nb][j] + bv);
          out[(size_t)(row + j) * Ndim + col] = __float2bfloat16(g);
        }
      }
    }
  } else {
    float* out = (float*)outbase + (size_t)b * Mdim * Ndim;
#pragma unroll
    for (int mb = 0; mb < 4; ++mb) {
      const int row = r0 + wr * 64 + mb * 16 + lq * 4;
#pragma unroll
      for (int nb = 0; nb < 4; ++nb) {
        const int col = n0 + wc * 64 + nb * 16 + lrow;
        const float bv = bias[col];
#pragma unroll
        for (int j = 0; j < 4; ++j)
          out[(size_t)(row + j) * Ndim + col] = acc[mb][nb][j] + bv;
      }
    }
  }
}

// ---------------------------------------------------------------------------
extern "C" void kernel_launch(void* const* d_in, const int* in_sizes, int n_in,
                              void* d_out, int out_size, void* d_ws, size_t ws_size,
                              hipStream_t stream) {
  const float* x      = (const float*)d_in[0];
  const float* cond   = (const float*)d_in[1];
  const int*   route  = (const int*)d_in[2];
  const float* W_cond = (const float*)d_in[3];
  const float* b_cond = (const float*)d_in[4];
  const float* W1     = (const float*)d_in[5];
  const float* b1     = (const float*)d_in[6];
  const float* W2     = (const float*)d_in[7];
  const float* b2     = (const float*)d_in[8];
  float* out = (float*)d_out;

  // workspace layout (bytes)
  const size_t SS_OFF   = 0;
  const size_t XMOD_OFF = 32768;
  const size_t W1T_OFF  = XMOD_OFF + (size_t)BATCH * NTOK * DDIM * 2;
  const size_t W2T_OFF  = W1T_OFF + (size_t)NEXP * DDIM * DFFDIM * 2;
  const size_t H_OFF    = W2T_OFF + (size_t)NEXP * DFFDIM * DDIM * 2;
  const size_t NEED     = H_OFF + (size_t)BATCH * NTOK * DFFDIM * 2;
  if (ws_size < NEED) return;

  char* ws = (char*)d_ws;
  float* ss            = (float*)(ws + SS_OFF);
  __hip_bfloat16* xmod = (__hip_bfloat16*)(ws + XMOD_OFF);
  __hip_bfloat16* w1t  = (__hip_bfloat16*)(ws + W1T_OFF);
  __hip_bfloat16* w2t  = (__hip_bfloat16*)(ws + W2T_OFF);
  __hip_bfloat16* h    = (__hip_bfloat16*)(ws + H_OFF);

  // 1) cond modulation
  mod_kernel<<<dim3(2 * DDIM / 64, BATCH), 256, 0, stream>>>(cond, route, W_cond, b_cond, ss);

  // 2) FiLM -> bf16 (8 elems/thread): B*N*D/8 / 256 = 4096 blocks
  {
    const size_t groups = (size_t)BATCH * NTOK * DDIM / 8;
    film_kernel<<<(unsigned)(groups / 256), 256, 0, stream>>>(x, ss, xmod);
  }

  // 3) weight transpose+convert, 64x64 tiles (routed experts only)
  transpose_cvt<<<dim3(DFFDIM / 64, DDIM / 64, NEXP), 256, 0, stream>>>(W1, w1t, DDIM, DFFDIM, route);
  transpose_cvt<<<dim3(DDIM / 64, DFFDIM / 64, NEXP), 256, 0, stream>>>(W2, w2t, DFFDIM, DDIM, route);

  // 4) GEMM1 (R12-proven 4-barrier 8-phase): grid 8*8*8 = 512 blocks
  gemm_8ph<0><<<(NTOK / 256) * (DFFDIM / 256) * BATCH, 512, 0, stream>>>(
      xmod, w1t, b1, h, route, NTOK, DFFDIM, DDIM, NTOK / 256);

  // 5) GEMM2 (db2 control): grid 16*4*8 = 512 blocks
  gemm_db2<1><<<(NTOK / 128) * (DDIM / 128) * BATCH, 256, 0, stream>>>(
      h, w2t, b2, out, route, NTOK, DDIM, DFFDIM, NTOK / 128);
}